// Round 6
// baseline (1120.657 us; speedup 1.0000x reference)
//
#include <hip/hip_runtime.h>
#include <stdint.h>

#define D 128
#define E_EDGES 600000
#define E2 1200000
#define N_USER_C 100000
#define N_ITEM_C 50000
#define NSEG_TOT 150000
#define NEG_SLOPE 0.01f
#define LN_EPS 1e-5f

#define CAP 48               // bucket capacity; P(Poisson(12) > 48) ~ 1e-15 per node
#define NB 4                 // nodes per steal batch
#define GRID_BLOCKS 768      // 3 blocks/CU at (256,3): whole grid resident, one round
#define CVT_BLOCKS 1024      // blocks of prep_k doing the fp16 convert

typedef __attribute__((ext_vector_type(8))) _Float16 f16x8;
typedef __attribute__((ext_vector_type(4))) float f32x4;
typedef __attribute__((ext_vector_type(2))) float f32x2;

// ---------------- fused prep: fp32->fp16 convert + bucket CSR fill ----------------
// One dispatch; block ranges do independent jobs (overlap streaming with atomics).
__global__ void prep_k(const float* __restrict__ xu, const float* __restrict__ xi,
                       _Float16* __restrict__ xuh, _Float16* __restrict__ xih,
                       _Float16* __restrict__ zrow,
                       const int* __restrict__ esrc_ui, const int* __restrict__ edst_ui,
                       const int* __restrict__ esrc_iu, const int* __restrict__ edst_iu,
                       int* __restrict__ cnt, int* __restrict__ bucket) {
    const int b = blockIdx.x;
    if (b < CVT_BLOCKS) {
        // fp16 convert: halves gather bytes (512->256 B/row) and removes
        // per-chunk cvt VALU work in the main kernel. Also zero-fills zrow.
        int tid = b * 256 + threadIdx.x;
        if (tid < 32) ((uint2*)zrow)[tid] = (uint2){0u, 0u};
        const int NU4 = N_USER_C * 32;        // float4 count, user block
        const int NT4 = NU4 + N_ITEM_C * 32;
        for (int v = tid; v < NT4; v += CVT_BLOCKS * 256) {
            const bool isu = v < NU4;
            const float4 f = isu ? ((const float4*)xu)[v] : ((const float4*)xi)[v - NU4];
            _Float16* o = isu ? (xuh + (size_t)v * 4) : (xih + (size_t)(v - NU4) * 4);
            uint2 p;
            p.x = __builtin_bit_cast(uint32_t, __builtin_amdgcn_cvt_pkrtz(f.x, f.y));
            p.y = __builtin_bit_cast(uint32_t, __builtin_amdgcn_cvt_pkrtz(f.z, f.w));
            *(uint2*)o = p;
        }
    } else {
        // bucket fill. Unified dst space: [0,50000) items (rel u->i),
        // [50000,150000) users (rel i->u). cnt[c] ends as degree(c).
        int e = (b - CVT_BLOCKS) * 256 + threadIdx.x;
        int s, c;
        if (e < E_EDGES) { s = esrc_ui[e];           c = edst_ui[e]; }
        else if (e < E2) { s = esrc_iu[e - E_EDGES]; c = N_ITEM_C + edst_iu[e - E_EDGES]; }
        else return;
        int pos = atomicAdd(&cnt[c], 1);
        if (pos < CAP)   // statistically never dropped
            bucket[(size_t)c * CAP + pos] = s;
    }
}

// ---------------- fused NGCF conv + LayerNorm/ReLU, work-stealing ----------------
// One wave per dst node; verified round-4/5 compute core (fragment-major LDS W,
// SQ_LDS_BANK_CONFLICT=0; fp16 gathers 4x16B/lane; bias preloaded in acc;
// padded lanes read zrow; padded rows' leaky(bias) removed in closed form).
// This round: single merged chunk loop (chunk0 indices from the 1-node-ahead
// metadata prefetch), relation templated (all uniform scalars), and
// __launch_bounds__(256,3): cap ~170 unified regs, 3 waves/SIMD.
//   - (256,2) measured: occupancy pinned at 2 waves/SIMD (23%) and 1.295 GB
//     of suspected unified-file spill writes (WRITE_SIZE identical across
//     NT/no-NT builds -> deterministic, not store amplification).
//   - (256,4) measured: catastrophic spill (round 2: 4.4 GB writes). If
//     (256,3) spills too (WRITE_SIZE >> 0.2 GB next profile), revert to 2.
template<int REL>
__device__ __forceinline__ void conv_body(
    const _Float16* __restrict__ xsh, const _Float16* __restrict__ xdh,
    const float* __restrict__ bp, const float* __restrict__ lnw,
    const float* __restrict__ lnb, const int* __restrict__ cnt,
    const int* __restrict__ bucket, int* __restrict__ ctr,
    const _Float16* __restrict__ zrow, float* __restrict__ outp,
    const _Float16* WtF)
{
    constexpr int n_dst = REL ? N_USER_C : N_ITEM_C;
    constexpr int cbase = REL ? N_ITEM_C : 0;

    const int t = threadIdx.x;
    const int l    = t & 63;
    const int lo16 = l & 15;
    const int quad = l >> 4;
    const int n0 = 2 * quad, n1 = n0 + 1;
    const int col0 = n0 * 16 + lo16, col1 = n1 * 16 + lo16;

    float bn[8];
    #pragma unroll
    for (int n = 0; n < 8; n++) bn[n] = bp[n * 16 + lo16];
    const float lw0 = lnw[col0], lw1 = lnw[col1];
    const float lb0 = lnb[col0], lb1 = lnb[col1];

    while (true) {
        int g = 0;
        if (l == 0) g = atomicAdd(ctr, NB);
        g = __shfl(g, 0);
        if (g >= n_dst) break;
        const int gend = (g + NB < n_dst) ? g + NB : n_dst;

        // metadata prefetch, one node ahead (2 regs — the proven-safe depth)
        int len_c = cnt[cbase + g];
        len_c = len_c < CAP ? len_c : CAP;
        int idx_c = bucket[(size_t)(cbase + g) * CAP + lo16];

        for (int d = g; d < gend; ++d) {
            int len_n = 0, idx_n = 0;
            if (d + 1 < gend) {
                len_n = cnt[cbase + d + 1];
                len_n = len_n < CAP ? len_n : CAP;
                idx_n = bucket[(size_t)(cbase + d + 1) * CAP + lo16];
            }
            const int len = len_c;

            // dst row: 4 x 16B, 16 lanes broadcast per address
            const f16x8* pdh = (const f16x8*)(xdh + ((size_t)d << 7));
            f16x8 dr[4];
            #pragma unroll
            for (int kt = 0; kt < 4; kt++) dr[kt] = pdh[kt * 4 + quad];

            float nacc[8];
            #pragma unroll
            for (int n = 0; n < 8; n++) nacc[n] = 0.f;

            const int lim = len > 0 ? len : 1;   // len==0 still runs 1 zero-chunk
            for (int c0i = 0; c0i < lim; c0i += 16) {
                const int sj = (c0i == 0) ? idx_c
                             : bucket[(size_t)(cbase + d) * CAP + c0i + lo16];
                const bool okg = (c0i + lo16) < len;
                const f16x8* ps = okg ? (const f16x8*)(xsh + ((size_t)sj << 7))
                                      : (const f16x8*)zrow;
                f16x8 af[4];
                #pragma unroll
                for (int kt = 0; kt < 4; kt++) af[kt] = ps[kt * 4 + quad] * dr[kt];

                #pragma unroll
                for (int h = 0; h < 2; h++) {
                    f32x4 acc[4];
                    #pragma unroll
                    for (int n = 0; n < 4; n++) {
                        const float b = bn[h * 4 + n];
                        acc[n] = (f32x4){b, b, b, b};
                    }
                    #pragma unroll
                    for (int kt = 0; kt < 4; kt++) {
                        #pragma unroll
                        for (int n = 0; n < 4; n++) {
                            f16x8 bf = *(const f16x8*)&WtF[(((h * 4 + n) * 4 + kt) * 64 + l) * 8];
                            acc[n] = __builtin_amdgcn_mfma_f32_16x16x32_f16(af[kt], bf, acc[n], 0, 0, 0);
                        }
                    }
                    #pragma unroll
                    for (int n = 0; n < 4; n++) {
                        f32x2 v01 = (f32x2){acc[n][0], acc[n][1]};
                        f32x2 v23 = (f32x2){acc[n][2], acc[n][3]};
                        v01 = __builtin_elementwise_max(v01, v01 * NEG_SLOPE);
                        v23 = __builtin_elementwise_max(v23, v23 * NEG_SLOPE);
                        f32x2 vv = v01 + v23;
                        nacc[h * 4 + n] += vv.x + vv.y;
                    }
                }
            }

            // quad-reduce, remove padded-row leaky(bias); fused LN(node)+ReLU
            const int nch = (lim + 15) >> 4;
            const float inv = (float)((nch << 4) - len);
            float s1 = 0.f, s2 = 0.f;
            #pragma unroll
            for (int n = 0; n < 8; n++) {
                float s = nacc[n];
                s += __shfl_xor(s, 16);
                s += __shfl_xor(s, 32);
                s -= inv * fmaxf(bn[n], NEG_SLOPE * bn[n]);
                nacc[n] = s;
                s1 += s; s2 += s * s;
            }
            #pragma unroll
            for (int off = 1; off <= 8; off <<= 1) {
                s1 += __shfl_xor(s1, off);
                s2 += __shfl_xor(s2, off);
            }
            const float mu  = s1 * (1.0f / 128.0f);
            const float var = s2 * (1.0f / 128.0f) - mu * mu;
            const float rs  = rsqrtf(var + LN_EPS);

            float o0 = (nacc[n0] - mu) * rs * lw0 + lb0;
            float o1 = (nacc[n1] - mu) * rs * lw1 + lb1;
            float* rp = outp + ((size_t)d << 7);
            rp[col0] = fmaxf(o0, 0.f);   // plain stores: wave covers 8 full lines
            rp[col1] = fmaxf(o1, 0.f);

            len_c = len_n;
            idx_c = idx_n;
        }
    }
}

__global__ __launch_bounds__(256, 3) void ngcf_seg7(
    const _Float16* __restrict__ xuh, const _Float16* __restrict__ xih,
    const float* __restrict__ W_ui, const float* __restrict__ b_ui,
    const float* __restrict__ W_iu, const float* __restrict__ b_iu,
    const float* __restrict__ lnw_u, const float* __restrict__ lnb_u,
    const float* __restrict__ lnw_i, const float* __restrict__ lnb_i,
    const int* __restrict__ cnt, const int* __restrict__ bucket,
    int* __restrict__ ctrs, const _Float16* __restrict__ zrow,
    float* __restrict__ out_user, float* __restrict__ out_item)
{
    // fragment-major: WtF[(n*4+kt)*64 + lane][0..7] = W[kt*32+(lane>>4)*8+e][n*16+(lane&15)]
    // -> every ds_read_b128 lane-contiguous 16B (measured conflict-free)
    __shared__ _Float16 WtF[32 * 64 * 8];   // 32 KB

    const int rel = (blockIdx.x & 7) >= 3;   // 3:5 block split ~ edge+epilogue work ratio
    const float* __restrict__ Wp = rel ? W_iu : W_ui;

    const int t = threadIdx.x;
    for (int idx = t; idx < 2048; idx += 256) {
        const int frag = idx >> 6, lane = idx & 63;
        const int n = frag >> 2, kt = frag & 3;
        const int col = n * 16 + (lane & 15);
        const int k0  = kt * 32 + (lane >> 4) * 8;
        f16x8 v;
        #pragma unroll
        for (int e = 0; e < 8; e++) v[e] = (_Float16)Wp[(k0 + e) * 128 + col];
        *(f16x8*)&WtF[idx * 8] = v;
    }
    __syncthreads();   // only barrier; WtF read-only afterwards

    if (rel) conv_body<1>(xih, xuh, b_iu, lnw_u, lnb_u, cnt, bucket, ctrs + 1,
                          zrow, out_user, WtF);
    else     conv_body<0>(xuh, xih, b_ui, lnw_i, lnb_i, cnt, bucket, ctrs + 0,
                          zrow, out_item, WtF);
}

// ---------------- launch ----------------

extern "C" void kernel_launch(void* const* d_in, const int* in_sizes, int n_in,
                              void* d_out, int out_size, void* d_ws, size_t ws_size,
                              hipStream_t stream) {
    const float* x_user    = (const float*)d_in[0];
    const float* x_item    = (const float*)d_in[1];
    const float* W_ui      = (const float*)d_in[2];
    const float* b_ui      = (const float*)d_in[3];
    const float* W_iu      = (const float*)d_in[4];
    const float* b_iu      = (const float*)d_in[5];
    const float* ln_w_user = (const float*)d_in[6];
    const float* ln_b_user = (const float*)d_in[7];
    const float* ln_w_item = (const float*)d_in[8];
    const float* ln_b_item = (const float*)d_in[9];
    const int* esrc_ui = (const int*)d_in[10];
    const int* edst_ui = (const int*)d_in[11];
    const int* esrc_iu = (const int*)d_in[12];
    const int* edst_iu = (const int*)d_in[13];

    float* out = (float*)d_out;
    float* out_user = out;                          // N_USER x D
    float* out_item = out + (size_t)N_USER_C * D;   // N_ITEM x D

    // ws layout: cnt[150016] ints (steal ctrs at [150000..150001]) | bucket[150000*CAP]
    //            | zrow[128 halves] | xuh[100000*128 halves] | xih[50000*128 halves]
    int* cnt       = (int*)d_ws;
    int* ctrs      = cnt + NSEG_TOT;
    int* bucket    = cnt + 150016;
    _Float16* zrow = (_Float16*)(bucket + (size_t)NSEG_TOT * CAP);
    _Float16* xuh  = zrow + 128;
    _Float16* xih  = xuh + (size_t)N_USER_C * D;

    hipMemsetAsync(cnt, 0, (size_t)150016 * sizeof(int), stream);

    prep_k<<<dim3(CVT_BLOCKS + (E2 + 255) / 256), dim3(256), 0, stream>>>(
        x_user, x_item, xuh, xih, zrow,
        esrc_ui, edst_ui, esrc_iu, edst_iu, cnt, bucket);

    ngcf_seg7<<<dim3(GRID_BLOCKS), dim3(256), 0, stream>>>(
        xuh, xih, W_ui, b_ui, W_iu, b_iu,
        ln_w_user, ln_b_user, ln_w_item, ln_b_item,
        cnt, bucket, ctrs, zrow, out_user, out_item);
}

// Round 7
// 536.914 us; speedup vs baseline: 2.0872x; 2.0872x over previous
//
#include <hip/hip_runtime.h>
#include <stdint.h>

#define D 128
#define E_EDGES 600000
#define E2 1200000
#define N_USER_C 100000
#define N_ITEM_C 50000
#define NSEG_TOT 150000
#define NCPAD 150528          // 147*1024 scan padding
#define NSCAN_BLOCKS 147
#define NEG_SLOPE 0.01f
#define LN_EPS 1e-5f

#define GRID_BLOCKS 1280      // conv: 5 blocks/CU by LDS(32KB); static stride
#define HIST_BLOCKS ((E2 + 255) / 256)
#define CVT_BLOCKS 1024

typedef __attribute__((ext_vector_type(8))) _Float16 f16x8;
typedef __attribute__((ext_vector_type(4))) float f32x4;
typedef __attribute__((ext_vector_type(2))) float f32x2;

// ---------------- prep: histogram (joint dst space) + fp32->fp16 convert ----------------
// One dispatch, independent block ranges overlap atomic-bound hist with
// streaming convert. Joint dst space: [0,50000) item dst (rel u->i),
// [50000,150000) user dst (rel i->u).
__global__ void prep_k(const int* __restrict__ edst_ui, const int* __restrict__ edst_iu,
                       int* __restrict__ counts,
                       const float* __restrict__ xu, const float* __restrict__ xi,
                       _Float16* __restrict__ xuh, _Float16* __restrict__ xih,
                       _Float16* __restrict__ zrow) {
    const int b = blockIdx.x;
    if (b < HIST_BLOCKS) {
        int e = b * 256 + threadIdx.x;
        if (e < E_EDGES)      atomicAdd(&counts[edst_ui[e]], 1);
        else if (e < E2)      atomicAdd(&counts[N_ITEM_C + edst_iu[e - E_EDGES]], 1);
    } else {
        int tid = (b - HIST_BLOCKS) * 256 + threadIdx.x;
        if (tid < 32) ((uint2*)zrow)[tid] = (uint2){0u, 0u};   // 256 B fp16 zeros
        const int NU4 = N_USER_C * 32;        // float4 count, user block
        const int NT4 = NU4 + N_ITEM_C * 32;
        for (int v = tid; v < NT4; v += CVT_BLOCKS * 256) {
            const bool isu = v < NU4;
            const float4 f = isu ? ((const float4*)xu)[v] : ((const float4*)xi)[v - NU4];
            _Float16* o = isu ? (xuh + (size_t)v * 4) : (xih + (size_t)(v - NU4) * 4);
            uint2 p;
            p.x = __builtin_bit_cast(uint32_t, __builtin_amdgcn_cvt_pkrtz(f.x, f.y));
            p.y = __builtin_bit_cast(uint32_t, __builtin_amdgcn_cvt_pkrtz(f.z, f.w));
            *(uint2*)o = p;
        }
    }
}

// ---------------- joint exclusive scan (3 kernels, proven round-1) ----------------
__global__ void scan_block_k(const int* __restrict__ counts, int* __restrict__ offsets,
                             int* __restrict__ partial, int n) {
    __shared__ int sm[1024];
    const int t = threadIdx.x;
    const int i = blockIdx.x * 1024 + t;
    int v = (i < n) ? counts[i] : 0;
    sm[t] = v;
    __syncthreads();
    for (int off = 1; off < 1024; off <<= 1) {
        int x = (t >= off) ? sm[t - off] : 0;
        __syncthreads();
        sm[t] += x;
        __syncthreads();
    }
    if (i < n) offsets[i] = sm[t] - v;          // exclusive within block
    if (t == 1023) partial[blockIdx.x] = sm[t];
}

__global__ void scan_part_k(int* __restrict__ partial, int nb) {
    __shared__ int sm[256];
    const int t = threadIdx.x;
    int v = (t < nb) ? partial[t] : 0;
    sm[t] = v;
    __syncthreads();
    for (int off = 1; off < 256; off <<= 1) {
        int x = (t >= off) ? sm[t - off] : 0;
        __syncthreads();
        sm[t] += x;
        __syncthreads();
    }
    if (t < nb) partial[t] = sm[t] - v;
}

__global__ void scan_add_k(int* __restrict__ offsets, const int* __restrict__ partial,
                           int* __restrict__ counts, int n) {
    const int i = blockIdx.x * 1024 + threadIdx.x;
    if (i < n) {
        offsets[i] += partial[blockIdx.x];
        counts[i] = 0;                           // re-zero for scatter's atomics
    }
}

__global__ void scatter_k(const int* __restrict__ esrc_ui, const int* __restrict__ edst_ui,
                          const int* __restrict__ esrc_iu, const int* __restrict__ edst_iu,
                          const int* __restrict__ offsets, int* __restrict__ counts,
                          int* __restrict__ sorted) {
    int e = blockIdx.x * 256 + threadIdx.x;
    int s, c;
    if (e < E_EDGES)      { s = esrc_ui[e];            c = edst_ui[e]; }
    else if (e < E2)      { s = esrc_iu[e - E_EDGES];  c = N_ITEM_C + edst_iu[e - E_EDGES]; }
    else return;
    int pos = offsets[c] + atomicAdd(&counts[c], 1);
    sorted[pos] = s;
}

// ---------------- fused NGCF conv + LayerNorm/ReLU ----------------
// Round-0's verified structure (one dispatch PER RELATION, full GPU each,
// static d-stride — every restructure of this since round 0 measured slower)
// + the isolated wins: fp16 pre-converted gathers (4 x 16B/lane),
// fragment-major LDS W (SQ_LDS_BANK_CONFLICT 1.4e7 -> 0, measured round 4),
// bias preloaded in accumulator + zrow for padded lanes + closed-form
// removal of padded rows' leaky(bias), 1-node-ahead metadata prefetch
// (3 regs; deeper row-data prefetch measured to spill, rounds 2/3).
// __launch_bounds__(256,2): (256,3) measured VGPR=84 + 2.5 GB spill FETCH;
// (256,4) measured catastrophic. Demand is ~128 arch VGPRs: keep 2.
__global__ __launch_bounds__(256, 2) void conv_k(
    const _Float16* __restrict__ xsh, const _Float16* __restrict__ xdh,
    const float* __restrict__ Wp, const float* __restrict__ bp,
    const float* __restrict__ lnw, const float* __restrict__ lnb,
    const int* __restrict__ offsets, const int* __restrict__ sorted,
    const _Float16* __restrict__ zrow, float* __restrict__ outp,
    int n_dst, int cbase)
{
    // fragment-major: WtF[(n*4+kt)*64 + lane][0..7] = W[kt*32+(lane>>4)*8+e][n*16+(lane&15)]
    // -> every ds_read_b128 is lane-contiguous 16B (conflict-free, measured)
    __shared__ _Float16 WtF[32 * 64 * 8];   // 32 KB

    const int t = threadIdx.x;
    for (int idx = t; idx < 2048; idx += 256) {
        const int frag = idx >> 6, lane = idx & 63;
        const int n = frag >> 2, kt = frag & 3;
        const int col = n * 16 + (lane & 15);
        const int k0  = kt * 32 + (lane >> 4) * 8;
        f16x8 v;
        #pragma unroll
        for (int e = 0; e < 8; e++) v[e] = (_Float16)Wp[(k0 + e) * 128 + col];
        *(f16x8*)&WtF[idx * 8] = v;
    }
    __syncthreads();   // only barrier; WtF read-only afterwards

    const int l    = t & 63;
    const int lo16 = l & 15;
    const int quad = l >> 4;
    const int n0 = 2 * quad, n1 = n0 + 1;
    const int col0 = n0 * 16 + lo16, col1 = n1 * 16 + lo16;

    float bn[8];
    #pragma unroll
    for (int n = 0; n < 8; n++) bn[n] = bp[n * 16 + lo16];
    const float lw0 = lnw[col0], lw1 = lnw[col1];
    const float lb0 = lnb[col0], lb1 = lnb[col1];

    const int stride = GRID_BLOCKS * 4;
    int d = blockIdx.x * 4 + (t >> 6);   // grid-waves << n_dst: no early-exit path

    // ---- prologue: prefetch node d metadata (start, end, 16 src indices) ----
    int st_c = offsets[cbase + d];
    int en_c = (cbase + d + 1 < NSEG_TOT) ? offsets[cbase + d + 1] : E2;
    int idx_c = sorted[st_c + lo16];   // sorted padded by 16 ints; masked if past len

    while (d < n_dst) {
        const int dn = d + stride;
        int st_n = 0, en_n = 0, idx_n = 0;
        if (dn < n_dst) {              // issue next node's metadata NOW
            st_n = offsets[cbase + dn];
            en_n = (cbase + dn + 1 < NSEG_TOT) ? offsets[cbase + dn + 1] : E2;
            idx_n = sorted[st_n + lo16];
        }
        const int start = st_c;
        const int len   = en_c - st_c;

        // dst row: 4 x 16B, 16 lanes broadcast per address
        const f16x8* pdh = (const f16x8*)(xdh + ((size_t)d << 7));
        f16x8 dr[4];
        #pragma unroll
        for (int kt = 0; kt < 4; kt++) dr[kt] = pdh[kt * 4 + quad];

        float nacc[8];
        #pragma unroll
        for (int n = 0; n < 8; n++) nacc[n] = 0.f;

        const int lim = len > 0 ? len : 1;   // len==0 runs one all-zero chunk
        for (int c0i = 0; c0i < lim; c0i += 16) {
            const int sj = (c0i == 0) ? idx_c : sorted[start + c0i + lo16];
            const bool okg = (c0i + lo16) < len;   // overflow lanes read zrow
            const f16x8* ps = okg ? (const f16x8*)(xsh + ((size_t)sj << 7))
                                  : (const f16x8*)zrow;
            f16x8 af[4];
            #pragma unroll
            for (int kt = 0; kt < 4; kt++) af[kt] = ps[kt * 4 + quad] * dr[kt];

            #pragma unroll
            for (int h = 0; h < 2; h++) {
                f32x4 acc[4];
                #pragma unroll
                for (int n = 0; n < 4; n++) {
                    const float b = bn[h * 4 + n];
                    acc[n] = (f32x4){b, b, b, b};
                }
                #pragma unroll
                for (int kt = 0; kt < 4; kt++) {
                    #pragma unroll
                    for (int n = 0; n < 4; n++) {
                        f16x8 bf = *(const f16x8*)&WtF[(((h * 4 + n) * 4 + kt) * 64 + l) * 8];
                        acc[n] = __builtin_amdgcn_mfma_f32_16x16x32_f16(af[kt], bf, acc[n], 0, 0, 0);
                    }
                }
                #pragma unroll
                for (int n = 0; n < 4; n++) {
                    f32x2 v01 = (f32x2){acc[n][0], acc[n][1]};
                    f32x2 v23 = (f32x2){acc[n][2], acc[n][3]};
                    v01 = __builtin_elementwise_max(v01, v01 * NEG_SLOPE);
                    v23 = __builtin_elementwise_max(v23, v23 * NEG_SLOPE);
                    f32x2 vv = v01 + v23;
                    nacc[h * 4 + n] += vv.x + vv.y;
                }
            }
        }

        // quad-reduce, remove padded-row leaky(bias); fused LN(node)+ReLU
        const int nch = (lim + 15) >> 4;
        const float inv = (float)((nch << 4) - len);
        float s1 = 0.f, s2 = 0.f;
        #pragma unroll
        for (int n = 0; n < 8; n++) {
            float s = nacc[n];
            s += __shfl_xor(s, 16);
            s += __shfl_xor(s, 32);
            s -= inv * fmaxf(bn[n], NEG_SLOPE * bn[n]);
            nacc[n] = s;
            s1 += s; s2 += s * s;
        }
        #pragma unroll
        for (int off = 1; off <= 8; off <<= 1) {
            s1 += __shfl_xor(s1, off);
            s2 += __shfl_xor(s2, off);
        }
        const float mu  = s1 * (1.0f / 128.0f);
        const float var = s2 * (1.0f / 128.0f) - mu * mu;
        const float rs  = rsqrtf(var + LN_EPS);

        float o0 = (nacc[n0] - mu) * rs * lw0 + lb0;
        float o1 = (nacc[n1] - mu) * rs * lw1 + lb1;
        float* rp = outp + ((size_t)d << 7);
        rp[col0] = fmaxf(o0, 0.f);   // wave covers the full 512B row: 8 whole lines
        rp[col1] = fmaxf(o1, 0.f);

        st_c = st_n; en_c = en_n; idx_c = idx_n;
        d = dn;
    }
}

// ---------------- launch ----------------

extern "C" void kernel_launch(void* const* d_in, const int* in_sizes, int n_in,
                              void* d_out, int out_size, void* d_ws, size_t ws_size,
                              hipStream_t stream) {
    const float* x_user    = (const float*)d_in[0];
    const float* x_item    = (const float*)d_in[1];
    const float* W_ui      = (const float*)d_in[2];
    const float* b_ui      = (const float*)d_in[3];
    const float* W_iu      = (const float*)d_in[4];
    const float* b_iu      = (const float*)d_in[5];
    const float* ln_w_user = (const float*)d_in[6];
    const float* ln_b_user = (const float*)d_in[7];
    const float* ln_w_item = (const float*)d_in[8];
    const float* ln_b_item = (const float*)d_in[9];
    const int* esrc_ui = (const int*)d_in[10];
    const int* edst_ui = (const int*)d_in[11];
    const int* esrc_iu = (const int*)d_in[12];
    const int* edst_iu = (const int*)d_in[13];

    float* out = (float*)d_out;
    float* out_user = out;                          // N_USER x D
    float* out_item = out + (size_t)N_USER_C * D;   // N_ITEM x D

    // ws (ints): counts[NCPAD] | offsets[NCPAD] | partial[256] | sorted[E2+16]
    //            | zrow[256 halves] | xuh[100000*128 halves] | xih[50000*128 halves]
    int* counts  = (int*)d_ws;
    int* offsets = counts + NCPAD;
    int* partial = offsets + NCPAD;
    int* sorted  = partial + 256;
    _Float16* zrow = (_Float16*)(sorted + E2 + 16);
    _Float16* xuh  = zrow + 256;
    _Float16* xih  = xuh + (size_t)N_USER_C * D;

    hipMemsetAsync(counts, 0, (size_t)NCPAD * sizeof(int), stream);

    prep_k<<<dim3(HIST_BLOCKS + CVT_BLOCKS), dim3(256), 0, stream>>>(
        edst_ui, edst_iu, counts, x_user, x_item, xuh, xih, zrow);

    scan_block_k<<<dim3(NSCAN_BLOCKS), dim3(1024), 0, stream>>>(counts, offsets, partial, NCPAD);
    scan_part_k<<<dim3(1), dim3(256), 0, stream>>>(partial, NSCAN_BLOCKS);
    scan_add_k<<<dim3(NSCAN_BLOCKS), dim3(1024), 0, stream>>>(offsets, partial, counts, NCPAD);

    scatter_k<<<dim3(HIST_BLOCKS), dim3(256), 0, stream>>>(
        esrc_ui, edst_ui, esrc_iu, edst_iu, offsets, counts, sorted);

    // relation u->i: aggregate at items (dst space [0,50000))
    conv_k<<<dim3(GRID_BLOCKS), dim3(256), 0, stream>>>(
        xuh, xih, W_ui, b_ui, ln_w_item, ln_b_item,
        offsets, sorted, zrow, out_item, N_ITEM_C, 0);
    // relation i->u: aggregate at users (dst space [50000,150000))
    conv_k<<<dim3(GRID_BLOCKS), dim3(256), 0, stream>>>(
        xih, xuh, W_iu, b_iu, ln_w_user, ln_b_user,
        offsets, sorted, zrow, out_user, N_USER_C, N_ITEM_C);
}

// Round 8
// 517.693 us; speedup vs baseline: 2.1647x; 1.0371x over previous
//
#include <hip/hip_runtime.h>
#include <stdint.h>

#define D 128
#define E_EDGES 600000
#define E2 1200000
#define N_USER_C 100000
#define N_ITEM_C 50000
#define NSEG_TOT 150000
#define NCPAD 150528          // 147*1024 scan padding
#define NSCAN_BLOCKS 147
#define NEG_SLOPE 0.01f
#define LN_EPS 1e-5f

#define CONV_BLOCKS 1280      // fused conv grid
#define ITEM_BLOCKS 480       // 3:5 split ~ chunk+epilogue work ratio (58k:102k chunks)
#define HIST_BLOCKS ((E2 + 255) / 256)
#define CVT_BLOCKS 1024

typedef __attribute__((ext_vector_type(8))) _Float16 f16x8;
typedef __attribute__((ext_vector_type(4))) float f32x4;
typedef __attribute__((ext_vector_type(2))) float f32x2;

// ---------------- prep: histogram + fp32->fp16 convert + flag init ----------------
// One dispatch, independent block ranges. Joint dst space: [0,50000) item dst
// (rel u->i), [50000,150000) user dst (rel i->u).
__global__ void prep_k(const int* __restrict__ edst_ui, const int* __restrict__ edst_iu,
                       int* __restrict__ counts, int* __restrict__ totals,
                       const float* __restrict__ xu, const float* __restrict__ xi,
                       _Float16* __restrict__ xuh, _Float16* __restrict__ xih,
                       _Float16* __restrict__ zrow) {
    const int b = blockIdx.x;
    if (b < HIST_BLOCKS) {
        int e = b * 256 + threadIdx.x;
        if (e < E_EDGES)      atomicAdd(&counts[edst_ui[e]], 1);
        else if (e < E2)      atomicAdd(&counts[N_ITEM_C + edst_iu[e - E_EDGES]], 1);
    } else {
        int tid = (b - HIST_BLOCKS) * 256 + threadIdx.x;
        if (b == HIST_BLOCKS) {
            if (threadIdx.x < 160) totals[threadIdx.x] = -1;   // lookback sentinels
            if (threadIdx.x < 32) ((uint2*)zrow)[threadIdx.x] = (uint2){0u, 0u};
        }
        const int NU4 = N_USER_C * 32;        // float4 count, user block
        const int NT4 = NU4 + N_ITEM_C * 32;
        for (int v = tid; v < NT4; v += CVT_BLOCKS * 256) {
            const bool isu = v < NU4;
            const float4 f = isu ? ((const float4*)xu)[v] : ((const float4*)xi)[v - NU4];
            _Float16* o = isu ? (xuh + (size_t)v * 4) : (xih + (size_t)(v - NU4) * 4);
            uint2 p;
            p.x = __builtin_bit_cast(uint32_t, __builtin_amdgcn_cvt_pkrtz(f.x, f.y));
            p.y = __builtin_bit_cast(uint32_t, __builtin_amdgcn_cvt_pkrtz(f.z, f.w));
            *(uint2*)o = p;
        }
    }
}

// ---------------- single-pass exclusive scan (decoupled lookback) ----------------
// All 147 blocks co-resident (147 blks x 16 waves << capacity) -> spin is safe.
// Publishes per-block totals with release stores; each block sums its
// predecessors' totals (parallel lookback, no serialization in practice).
// Also re-zeroes counts for scatter's cursor atomics (was scan_add's job).
__global__ void scan_full_k(int* __restrict__ counts, int* __restrict__ offsets,
                            int* __restrict__ totals) {
    __shared__ int sm[1024];
    __shared__ int psum;
    const int t = threadIdx.x;
    const int b = blockIdx.x;
    const int i = b * 1024 + t;
    const int v = counts[i];               // NCPAD exact: no bounds check
    sm[t] = v;
    __syncthreads();
    for (int off = 1; off < 1024; off <<= 1) {
        int x = (t >= off) ? sm[t - off] : 0;
        __syncthreads();
        sm[t] += x;
        __syncthreads();
    }
    const int incl = sm[t];
    if (t == 1023)
        __hip_atomic_store(&totals[b], incl, __ATOMIC_RELEASE, __HIP_MEMORY_SCOPE_AGENT);
    if (t == 0) psum = 0;
    __syncthreads();
    if (t < b) {                           // up to 146 predecessor totals
        int x;
        do {
            x = __hip_atomic_load(&totals[t], __ATOMIC_ACQUIRE, __HIP_MEMORY_SCOPE_AGENT);
        } while (x < 0);
        atomicAdd(&psum, x);               // LDS atomic
    }
    __syncthreads();
    offsets[i] = incl - v + psum;          // global exclusive prefix
    counts[i] = 0;                         // cursor for scatter
}

__global__ void scatter_k(const int* __restrict__ esrc_ui, const int* __restrict__ edst_ui,
                          const int* __restrict__ esrc_iu, const int* __restrict__ edst_iu,
                          const int* __restrict__ offsets, int* __restrict__ counts,
                          int* __restrict__ sorted) {
    int e = blockIdx.x * 256 + threadIdx.x;
    int s, c;
    if (e < E_EDGES)      { s = esrc_ui[e];            c = edst_ui[e]; }
    else if (e < E2)      { s = esrc_iu[e - E_EDGES];  c = N_ITEM_C + edst_iu[e - E_EDGES]; }
    else return;
    int pos = offsets[c] + atomicAdd(&counts[c], 1);
    sorted[pos] = s;
}

// ---------------- fused NGCF conv + LayerNorm/ReLU, both relations ----------------
// Round-7 verified conv core (fp16 gathers 4x16B/lane; fragment-major LDS W,
// SQ_LDS_BANK_CONFLICT=0; bias preloaded in acc; zrow for padded lanes;
// closed-form removal of padded rows' leaky(bias); 1-node-ahead metadata
// prefetch). This round: ONE dispatch, static block-range split 3:5 between
// relations (fused+CSR+static measured write-clean in round 1; only
// bucket/steal variants produced the 1.2 GB phantom writes) -> the item
// relation's drain tail overlaps the user relation's work.
// __launch_bounds__(256,2): (256,3) measured VGPR=84 + 2.5 GB spill FETCH;
// (256,4) catastrophic. Demand ~128 arch VGPR: keep 2.
__global__ __launch_bounds__(256, 2) void conv2_k(
    const _Float16* __restrict__ xuh, const _Float16* __restrict__ xih,
    const float* __restrict__ W_ui, const float* __restrict__ b_ui,
    const float* __restrict__ W_iu, const float* __restrict__ b_iu,
    const float* __restrict__ lnw_u, const float* __restrict__ lnb_u,
    const float* __restrict__ lnw_i, const float* __restrict__ lnb_i,
    const int* __restrict__ offsets, const int* __restrict__ sorted,
    const _Float16* __restrict__ zrow,
    float* __restrict__ out_user, float* __restrict__ out_item)
{
    // fragment-major: WtF[(n*4+kt)*64 + lane][0..7] = W[kt*32+(lane>>4)*8+e][n*16+(lane&15)]
    __shared__ _Float16 WtF[32 * 64 * 8];   // 32 KB

    const int rel   = blockIdx.x >= ITEM_BLOCKS;
    const int bid_r = rel ? (blockIdx.x - ITEM_BLOCKS) : blockIdx.x;
    const int nblk  = rel ? (CONV_BLOCKS - ITEM_BLOCKS) : ITEM_BLOCKS;
    const _Float16* __restrict__ xsh = rel ? xih : xuh;
    const _Float16* __restrict__ xdh = rel ? xuh : xih;
    const float* __restrict__ Wp   = rel ? W_iu : W_ui;
    const float* __restrict__ bp   = rel ? b_iu : b_ui;
    const float* __restrict__ lnw  = rel ? lnw_u : lnw_i;
    const float* __restrict__ lnb  = rel ? lnb_u : lnb_i;
    float* __restrict__ outp       = rel ? out_user : out_item;
    const int n_dst = rel ? N_USER_C : N_ITEM_C;
    const int cbase = rel ? N_ITEM_C : 0;

    const int t = threadIdx.x;
    for (int idx = t; idx < 2048; idx += 256) {
        const int frag = idx >> 6, lane = idx & 63;
        const int n = frag >> 2, kt = frag & 3;
        const int col = n * 16 + (lane & 15);
        const int k0  = kt * 32 + (lane >> 4) * 8;
        f16x8 v;
        #pragma unroll
        for (int e = 0; e < 8; e++) v[e] = (_Float16)Wp[(k0 + e) * 128 + col];
        *(f16x8*)&WtF[idx * 8] = v;
    }
    __syncthreads();   // only barrier; WtF read-only afterwards

    const int l    = t & 63;
    const int lo16 = l & 15;
    const int quad = l >> 4;
    const int n0 = 2 * quad, n1 = n0 + 1;
    const int col0 = n0 * 16 + lo16, col1 = n1 * 16 + lo16;

    float bn[8];
    #pragma unroll
    for (int n = 0; n < 8; n++) bn[n] = bp[n * 16 + lo16];
    const float lw0 = lnw[col0], lw1 = lnw[col1];
    const float lb0 = lnb[col0], lb1 = lnb[col1];

    const int stride = nblk * 4;
    int d = bid_r * 4 + (t >> 6);

    // prologue: node d metadata (offsets[cbase+d+1] is always valid: padded scan)
    int st_c = offsets[cbase + d];
    int en_c = offsets[cbase + d + 1];
    int idx_c = sorted[st_c + lo16];   // sorted padded by 16 ints

    while (d < n_dst) {
        const int dn = d + stride;
        int st_n = 0, en_n = 0, idx_n = 0;
        if (dn < n_dst) {              // issue next node's metadata NOW
            st_n = offsets[cbase + dn];
            en_n = offsets[cbase + dn + 1];
            idx_n = sorted[st_n + lo16];
        }
        const int start = st_c;
        const int len   = en_c - st_c;

        // dst row: 4 x 16B, 16 lanes broadcast per address
        const f16x8* pdh = (const f16x8*)(xdh + ((size_t)d << 7));
        f16x8 dr[4];
        #pragma unroll
        for (int kt = 0; kt < 4; kt++) dr[kt] = pdh[kt * 4 + quad];

        float nacc[8];
        #pragma unroll
        for (int n = 0; n < 8; n++) nacc[n] = 0.f;

        const int lim = len > 0 ? len : 1;   // len==0 runs one all-zero chunk
        for (int c0i = 0; c0i < lim; c0i += 16) {
            const int sj = (c0i == 0) ? idx_c : sorted[start + c0i + lo16];
            const bool okg = (c0i + lo16) < len;   // overflow lanes read zrow
            const f16x8* ps = okg ? (const f16x8*)(xsh + ((size_t)sj << 7))
                                  : (const f16x8*)zrow;
            f16x8 af[4];
            #pragma unroll
            for (int kt = 0; kt < 4; kt++) af[kt] = ps[kt * 4 + quad] * dr[kt];

            #pragma unroll
            for (int h = 0; h < 2; h++) {
                f32x4 acc[4];
                #pragma unroll
                for (int n = 0; n < 4; n++) {
                    const float b = bn[h * 4 + n];
                    acc[n] = (f32x4){b, b, b, b};
                }
                #pragma unroll
                for (int kt = 0; kt < 4; kt++) {
                    #pragma unroll
                    for (int n = 0; n < 4; n++) {
                        f16x8 bf = *(const f16x8*)&WtF[(((h * 4 + n) * 4 + kt) * 64 + l) * 8];
                        acc[n] = __builtin_amdgcn_mfma_f32_16x16x32_f16(af[kt], bf, acc[n], 0, 0, 0);
                    }
                }
                #pragma unroll
                for (int n = 0; n < 4; n++) {
                    f32x2 v01 = (f32x2){acc[n][0], acc[n][1]};
                    f32x2 v23 = (f32x2){acc[n][2], acc[n][3]};
                    v01 = __builtin_elementwise_max(v01, v01 * NEG_SLOPE);
                    v23 = __builtin_elementwise_max(v23, v23 * NEG_SLOPE);
                    f32x2 vv = v01 + v23;
                    nacc[h * 4 + n] += vv.x + vv.y;
                }
            }
        }

        // quad-reduce, remove padded-row leaky(bias); fused LN(node)+ReLU
        const int nch = (lim + 15) >> 4;
        const float inv = (float)((nch << 4) - len);
        float s1 = 0.f, s2 = 0.f;
        #pragma unroll
        for (int n = 0; n < 8; n++) {
            float s = nacc[n];
            s += __shfl_xor(s, 16);
            s += __shfl_xor(s, 32);
            s -= inv * fmaxf(bn[n], NEG_SLOPE * bn[n]);
            nacc[n] = s;
            s1 += s; s2 += s * s;
        }
        #pragma unroll
        for (int off = 1; off <= 8; off <<= 1) {
            s1 += __shfl_xor(s1, off);
            s2 += __shfl_xor(s2, off);
        }
        const float mu  = s1 * (1.0f / 128.0f);
        const float var = s2 * (1.0f / 128.0f) - mu * mu;
        const float rs  = rsqrtf(var + LN_EPS);

        float o0 = (nacc[n0] - mu) * rs * lw0 + lb0;
        float o1 = (nacc[n1] - mu) * rs * lw1 + lb1;
        float* rp = outp + ((size_t)d << 7);
        rp[col0] = fmaxf(o0, 0.f);   // wave covers the full 512B row: 8 whole lines
        rp[col1] = fmaxf(o1, 0.f);

        st_c = st_n; en_c = en_n; idx_c = idx_n;
        d = dn;
    }
}

// ---------------- launch ----------------

extern "C" void kernel_launch(void* const* d_in, const int* in_sizes, int n_in,
                              void* d_out, int out_size, void* d_ws, size_t ws_size,
                              hipStream_t stream) {
    const float* x_user    = (const float*)d_in[0];
    const float* x_item    = (const float*)d_in[1];
    const float* W_ui      = (const float*)d_in[2];
    const float* b_ui      = (const float*)d_in[3];
    const float* W_iu      = (const float*)d_in[4];
    const float* b_iu      = (const float*)d_in[5];
    const float* ln_w_user = (const float*)d_in[6];
    const float* ln_b_user = (const float*)d_in[7];
    const float* ln_w_item = (const float*)d_in[8];
    const float* ln_b_item = (const float*)d_in[9];
    const int* esrc_ui = (const int*)d_in[10];
    const int* edst_ui = (const int*)d_in[11];
    const int* esrc_iu = (const int*)d_in[12];
    const int* edst_iu = (const int*)d_in[13];

    float* out = (float*)d_out;
    float* out_user = out;                          // N_USER x D
    float* out_item = out + (size_t)N_USER_C * D;   // N_ITEM x D

    // ws (ints): counts[NCPAD] | offsets[NCPAD] | totals[256] | sorted[E2+16]
    //            | zrow[256 halves] | xuh[100000*128 halves] | xih[50000*128 halves]
    int* counts  = (int*)d_ws;
    int* offsets = counts + NCPAD;
    int* totals  = offsets + NCPAD;
    int* sorted  = totals + 256;
    _Float16* zrow = (_Float16*)(sorted + E2 + 16);
    _Float16* xuh  = zrow + 256;
    _Float16* xih  = xuh + (size_t)N_USER_C * D;

    hipMemsetAsync(counts, 0, (size_t)NCPAD * sizeof(int), stream);

    prep_k<<<dim3(HIST_BLOCKS + CVT_BLOCKS), dim3(256), 0, stream>>>(
        edst_ui, edst_iu, counts, totals, x_user, x_item, xuh, xih, zrow);

    scan_full_k<<<dim3(NSCAN_BLOCKS), dim3(1024), 0, stream>>>(counts, offsets, totals);

    scatter_k<<<dim3(HIST_BLOCKS), dim3(256), 0, stream>>>(
        esrc_ui, edst_ui, esrc_iu, edst_iu, offsets, counts, sorted);

    conv2_k<<<dim3(CONV_BLOCKS), dim3(256), 0, stream>>>(
        xuh, xih, W_ui, b_ui, W_iu, b_iu,
        ln_w_user, ln_b_user, ln_w_item, ln_b_item,
        offsets, sorted, zrow, out_user, out_item);
}